// Round 9
// baseline (582.166 us; speedup 1.0000x reference)
//
#include <hip/hip_runtime.h>
#include <hip/hip_cooperative_groups.h>
#include <math.h>

namespace cg = cooperative_groups;

#define NN 100000
#define NE 1600000
#define D 64

#define PB 256                      // cooperative blocks: 1/CU — proven co-residency (r8)
#define BT 1024                     // threads/block (16 waves/CU; VGPR=128 fits 4 waves/SIMD)
#define BW 512                      // bucket width
#define BSH 9                       // log2(BW)
#define NB 196                      // ceil(NN/BW)
#define RR (2 * NB)                 // 392 rows (dst rows then src rows)
#define NQ (NE / 4)                 // int4 quads

typedef _Float16 h4v __attribute__((ext_vector_type(4)));
typedef _Float16 h8v __attribute__((ext_vector_type(8)));

// ================= ONE cooperative prep kernel =================
// Phase 0: t_h = fp16(x @ W1)                    (independent work)
// Phase 1: per-block coarse bucket counts -> cnt[row][block]
// Phase 2: row sums + in-place offsets
// Phase 3: partition scatter (LDS cursors) -> pbuf (dst-part), qloc (src-part)
// Phase 4: per-bucket finalize -> row_ptr, ndst, esrc, nsrc
__global__ __launch_bounds__(BT) void prep_kernel(
    const float* __restrict__ x, const int* __restrict__ src,
    const int* __restrict__ dst, const float* __restrict__ W1,
    int* __restrict__ cnt, int* __restrict__ rowsum,
    int* __restrict__ pbuf, int* __restrict__ qloc,
    int* __restrict__ row_ptr, float* __restrict__ nsrc,
    float* __restrict__ ndst, int* __restrict__ esrc,
    _Float16* __restrict__ t_h)
{
    cg::grid_group grid = cg::this_grid();
    __shared__ float Wlds[D * D];
    __shared__ int hD[NB], hS[NB];
    __shared__ int fh[BW], fcur[BW];

    int t = threadIdx.x, b = blockIdx.x;
    int lane = t & 63, w = t >> 6;
    int wid = b * (BT / 64) + w;

    for (int i = t; i < D * D; i += BT) Wlds[i] = W1[i];
    for (int i = t; i < NB; i += BT) { hD[i] = 0; hS[i] = 0; }
    __syncthreads();

    // ---- Phase 0: transform1 (no nsrc; applied per-edge in aggregate-1) ----
    {
        int g = lane >> 4, c = lane & 15;
        for (int q = wid; q < NN / 4; q += PB * (BT / 64)) {
            int node = q * 4 + g;
            float4 xv = *(const float4*)(x + (size_t)node * D + (c << 2));
            float4 acc = {0.f, 0.f, 0.f, 0.f};
#pragma unroll
            for (int k = 0; k < D; ++k) {
                int srcl = (g << 4) | (k >> 2);
                float comp = ((k & 3) == 0) ? xv.x : ((k & 3) == 1) ? xv.y
                           : ((k & 3) == 2) ? xv.z : xv.w;
                float xk = __shfl(comp, srcl, 64);
                float4 w4 = *(const float4*)(Wlds + k * D + (c << 2));
                acc.x += xk * w4.x; acc.y += xk * w4.y;
                acc.z += xk * w4.z; acc.w += xk * w4.w;
            }
            h4v o;
            o[0] = (_Float16)acc.x; o[1] = (_Float16)acc.y;
            o[2] = (_Float16)acc.z; o[3] = (_Float16)acc.w;
            *(h4v*)(t_h + (size_t)node * D + (c << 2)) = o;
        }
    }

    // ---- Phase 1: count ----
    const int4* s4 = (const int4*)src;
    const int4* d4 = (const int4*)dst;
    for (int i = b * BT + t; i < NQ; i += PB * BT) {
        int4 a = s4[i];
        int4 d = d4[i];
        atomicAdd(&hS[a.x >> BSH], 1); atomicAdd(&hS[a.y >> BSH], 1);
        atomicAdd(&hS[a.z >> BSH], 1); atomicAdd(&hS[a.w >> BSH], 1);
        atomicAdd(&hD[d.x >> BSH], 1); atomicAdd(&hD[d.y >> BSH], 1);
        atomicAdd(&hD[d.z >> BSH], 1); atomicAdd(&hD[d.w >> BSH], 1);
    }
    __syncthreads();
    for (int i = t; i < NB; i += BT) {
        cnt[(size_t)i * PB + b] = hD[i];
        cnt[(size_t)(NB + i) * PB + b] = hS[i];
    }
    grid.sync();

    // ---- Phase 2a: row sums (one wave per row) ----
    if (wid < RR) {
        int s = 0;
        for (int i = lane; i < PB; i += 64) s += cnt[(size_t)wid * PB + i];
        for (int o = 32; o > 0; o >>= 1) s += __shfl_xor(s, o, 64);
        if (lane == 0) rowsum[wid] = s;
    }
    grid.sync();

    // ---- Phase 2b: in-place offsets (src rows continue at NE) ----
    if (wid < RR) {
        int ps = 0;
        for (int j = lane; j < wid; j += 64) ps += rowsum[j];
        for (int o = 32; o > 0; o >>= 1) ps += __shfl_xor(ps, o, 64);
        size_t base = (size_t)wid * PB + lane * 4;
        int v[4];
        int s = 0;
#pragma unroll
        for (int j = 0; j < 4; ++j) { v[j] = cnt[base + j]; s += v[j]; }
        int incl = s;
        for (int o = 1; o < 64; o <<= 1) {
            int u = __shfl_up(incl, o, 64);
            if (lane >= o) incl += u;
        }
        int run = ps + incl - s;
#pragma unroll
        for (int j = 0; j < 4; ++j) { cnt[base + j] = run; run += v[j]; }
    }
    grid.sync();

    // ---- Phase 3: partition scatter ----
    for (int i = t; i < NB; i += BT) {
        hD[i] = cnt[(size_t)i * PB + b];
        hS[i] = cnt[(size_t)(NB + i) * PB + b];
    }
    __syncthreads();
    for (int i = b * BT + t; i < NQ; i += PB * BT) {
        int4 a = s4[i];
        int4 d = d4[i];
        int p;
        p = atomicAdd(&hD[d.x >> BSH], 1); pbuf[p] = ((d.x & (BW - 1)) << 17) | a.x;
        p = atomicAdd(&hD[d.y >> BSH], 1); pbuf[p] = ((d.y & (BW - 1)) << 17) | a.y;
        p = atomicAdd(&hD[d.z >> BSH], 1); pbuf[p] = ((d.z & (BW - 1)) << 17) | a.z;
        p = atomicAdd(&hD[d.w >> BSH], 1); pbuf[p] = ((d.w & (BW - 1)) << 17) | a.w;
        p = atomicAdd(&hS[a.x >> BSH], 1); qloc[p - NE] = a.x & (BW - 1);
        p = atomicAdd(&hS[a.y >> BSH], 1); qloc[p - NE] = a.y & (BW - 1);
        p = atomicAdd(&hS[a.z >> BSH], 1); qloc[p - NE] = a.z & (BW - 1);
        p = atomicAdd(&hS[a.w >> BSH], 1); qloc[p - NE] = a.w & (BW - 1);
    }
    grid.sync();

    // ---- Phase 4: finalize, 392 tasks strided over 256 blocks ----
    for (int task = b; task < RR; task += PB) {
        if (task < NB) {
            int q = task;
            int beg = cnt[(size_t)q * PB];
            int end = (q + 1 < NB) ? cnt[(size_t)(q + 1) * PB] : NE;
            int lo = q << BSH;
            for (int i = t; i < BW; i += BT) fh[i] = 0;
            __syncthreads();
            for (int i = beg + t; i < end; i += BT) atomicAdd(&fh[pbuf[i] >> 17], 1);
            __syncthreads();
            if (w == 0) {                       // wave-0 scan: 8 bins/lane
                int v[8];
                int s = 0;
#pragma unroll
                for (int j = 0; j < 8; ++j) { v[j] = fh[lane * 8 + j]; s += v[j]; }
                int incl = s;
                for (int o = 1; o < 64; o <<= 1) {
                    int u = __shfl_up(incl, o, 64);
                    if (lane >= o) incl += u;
                }
                int run = incl - s;
#pragma unroll
                for (int j = 0; j < 8; ++j) {
                    int bin = lane * 8 + j;
                    fcur[bin] = run;
                    int n = lo + bin;
                    if (n < NN) {
                        row_ptr[n] = beg + run;
                        ndst[n] = 1.0f / sqrtf(fmaxf((float)v[j], 1.0f));
                    }
                    run += v[j];
                }
            }
            __syncthreads();
            for (int i = beg + t; i < end; i += BT) {
                int vv = pbuf[i];
                int p = atomicAdd(&fcur[vv >> 17], 1);
                esrc[beg + p] = vv & 0x1FFFF;
            }
            __syncthreads();
        } else {
            int q = task - NB;
            int beg = cnt[(size_t)(NB + q) * PB] - NE;
            int end = (q + 1 < NB) ? cnt[(size_t)(NB + q + 1) * PB] - NE : NE;
            int lo = q << BSH;
            for (int i = t; i < BW; i += BT) fh[i] = 0;
            __syncthreads();
            for (int i = beg + t; i < end; i += BT) atomicAdd(&fh[qloc[i]], 1);
            __syncthreads();
            for (int i = t; i < BW; i += BT) {
                int n = lo + i;
                if (n < NN) nsrc[n] = 1.0f / sqrtf(fmaxf((float)fh[i], 1.0f));
            }
            __syncthreads();
        }
    }
    if (b == 0 && t == 0) row_ptr[NN] = NE;
}

// ---------------- dense transform (layer 2): t[v] = fp16( nsrc[v] * (xin[v] @ W) ) --------
__global__ __launch_bounds__(256) void transform_kernel(const float* __restrict__ xin,
                                                        const float* __restrict__ W,
                                                        const float* __restrict__ nsrc,
                                                        _Float16* __restrict__ out) {
    __shared__ float Wlds[D * D];
    for (int i = threadIdx.x; i < D * D; i += 256) Wlds[i] = W[i];
    __syncthreads();
    int wave = (blockIdx.x * 256 + threadIdx.x) >> 6;
    int lane = threadIdx.x & 63;
    int g = lane >> 4, c = lane & 15;
    int node0 = wave * 4;
    if (node0 >= NN) return;
    int node = node0 + g;
    float4 xv = *(const float4*)(xin + (size_t)node * D + (c << 2));
    float4 acc = {0.f, 0.f, 0.f, 0.f};
#pragma unroll
    for (int k = 0; k < D; ++k) {
        int srcl = (g << 4) | (k >> 2);
        float comp = ((k & 3) == 0) ? xv.x : ((k & 3) == 1) ? xv.y
                   : ((k & 3) == 2) ? xv.z : xv.w;
        float xk = __shfl(comp, srcl, 64);
        float4 w4 = *(const float4*)(Wlds + k * D + (c << 2));
        acc.x += xk * w4.x; acc.y += xk * w4.y;
        acc.z += xk * w4.z; acc.w += xk * w4.w;
    }
    float sc = nsrc[node];
    h4v o;
    o[0] = (_Float16)(acc.x * sc); o[1] = (_Float16)(acc.y * sc);
    o[2] = (_Float16)(acc.z * sc); o[3] = (_Float16)(acc.w * sc);
    *(h4v*)(out + (size_t)node * D + (c << 2)) = o;
}

// ---------------- aggregation (fp16 gather, fp32 accumulate) ----------------
template<int RELU, int USE_NSRC>
__global__ __launch_bounds__(256) void aggregate_kernel(const _Float16* __restrict__ t,
                                                        const int* __restrict__ row_ptr,
                                                        const int* __restrict__ esrc,
                                                        const float* __restrict__ nsrc,
                                                        const float* __restrict__ ndst,
                                                        const float* __restrict__ bias,
                                                        float* __restrict__ out) {
    int node = (blockIdx.x * 256 + threadIdx.x) >> 6;
    int lane = threadIdx.x & 63;
    int g = lane >> 3, c = lane & 7;
    if (node >= NN) return;
    int beg = row_ptr[node], end = row_ptr[node + 1];
    float a0[8] = {0,0,0,0,0,0,0,0};
    float a1[8] = {0,0,0,0,0,0,0,0};
    int i = beg;
    for (; i + 16 <= end; i += 16) {
        int s0 = esrc[i + g];
        int s1 = esrc[i + 8 + g];
        float ns0 = USE_NSRC ? nsrc[s0] : 1.0f;
        float ns1 = USE_NSRC ? nsrc[s1] : 1.0f;
        h8v v0 = *(const h8v*)(t + (size_t)s0 * D + (c << 3));
        h8v v1 = *(const h8v*)(t + (size_t)s1 * D + (c << 3));
#pragma unroll
        for (int j = 0; j < 8; ++j) {
            if (USE_NSRC) { a0[j] += (float)v0[j] * ns0; a1[j] += (float)v1[j] * ns1; }
            else          { a0[j] += (float)v0[j];       a1[j] += (float)v1[j]; }
        }
    }
    for (; i < end; i += 8) {
        int e = i + g;
        if (e < end) {
            int s = esrc[e];
            float ns = USE_NSRC ? nsrc[s] : 1.0f;
            h8v v = *(const h8v*)(t + (size_t)s * D + (c << 3));
#pragma unroll
            for (int j = 0; j < 8; ++j) {
                if (USE_NSRC) a0[j] += (float)v[j] * ns;
                else          a0[j] += (float)v[j];
            }
        }
    }
#pragma unroll
    for (int j = 0; j < 8; ++j) a0[j] += a1[j];
#pragma unroll
    for (int j = 0; j < 8; ++j) {
        a0[j] += __shfl_xor(a0[j], 8, 64);
        a0[j] += __shfl_xor(a0[j], 16, 64);
        a0[j] += __shfl_xor(a0[j], 32, 64);
    }
    float nd = ndst[node];
    float4 blo = *(const float4*)(bias + (c << 3));
    float4 bhi = *(const float4*)(bias + (c << 3) + 4);
    float h[8];
    h[0] = a0[0] * nd + blo.x; h[1] = a0[1] * nd + blo.y;
    h[2] = a0[2] * nd + blo.z; h[3] = a0[3] * nd + blo.w;
    h[4] = a0[4] * nd + bhi.x; h[5] = a0[5] * nd + bhi.y;
    h[6] = a0[6] * nd + bhi.z; h[7] = a0[7] * nd + bhi.w;
    if (RELU) {
#pragma unroll
        for (int j = 0; j < 8; ++j) h[j] = fmaxf(h[j], 0.f);
    }
    if (g == 0) {
        float4 o0 = {h[0], h[1], h[2], h[3]};
        float4 o1 = {h[4], h[5], h[6], h[7]};
        *(float4*)(out + (size_t)node * D + (c << 3)) = o0;
        *(float4*)(out + (size_t)node * D + (c << 3) + 4) = o1;
    }
}

// ---------------- launcher ----------------
extern "C" void kernel_launch(void* const* d_in, const int* in_sizes, int n_in,
                              void* d_out, int out_size, void* d_ws, size_t ws_size,
                              hipStream_t stream) {
    const float* x  = (const float*)d_in[0];
    const int* src  = (const int*)d_in[1];
    const int* dst  = (const int*)d_in[2];
    const float* W1 = (const float*)d_in[3];
    const float* b1 = (const float*)d_in[4];
    const float* W2 = (const float*)d_in[5];
    const float* b2 = (const float*)d_in[6];
    float* out = (float*)d_out;

    size_t off = 0;
    auto alloc = [&](size_t bytes) -> void* {
        void* p = (char*)d_ws + off;
        off += (bytes + 255) & ~(size_t)255;
        return p;
    };
    int* row_ptr  = (int*)alloc((size_t)(NN + 1) * 4);
    float* nsrc   = (float*)alloc((size_t)NN * 4);
    float* ndst   = (float*)alloc((size_t)NN * 4);
    int* rowsum   = (int*)alloc((size_t)RR * 4);
    int* cnt      = (int*)alloc((size_t)RR * PB * 4);            // 0.4 MB
    int* esrc     = (int*)alloc((size_t)NE * 4);                 // 6.4 MB
    _Float16* t_h = (_Float16*)alloc((size_t)NN * D * 2);        // 12.8 MB
    float* h1     = (float*)alloc((size_t)NN * D * 4);           // 25.6 MB
    (void)ws_size;

    // prep scratch aliases h1 (dead until aggregate1): pbuf 6.4 | qloc 6.4
    int* pbuf = (int*)h1;
    int* qloc = pbuf + NE;

    void* args[] = { (void*)&x, (void*)&src, (void*)&dst, (void*)&W1,
                     (void*)&cnt, (void*)&rowsum, (void*)&pbuf, (void*)&qloc,
                     (void*)&row_ptr, (void*)&nsrc, (void*)&ndst, (void*)&esrc,
                     (void*)&t_h };
    hipLaunchCooperativeKernel((const void*)prep_kernel, dim3(PB), dim3(BT),
                               args, 0, stream);

    const int TB = 256;
    int tf_blocks = NN / 16;
    int ag_blocks = NN / 4;
    aggregate_kernel<1, 1><<<ag_blocks, TB, 0, stream>>>(t_h, row_ptr, esrc, nsrc, ndst, b1, h1);
    transform_kernel<<<tf_blocks, TB, 0, stream>>>(h1, W2, nsrc, t_h);
    aggregate_kernel<0, 0><<<ag_blocks, TB, 0, stream>>>(t_h, row_ptr, esrc, nsrc, ndst, b2, out);
}

// Round 10
// 291.436 us; speedup vs baseline: 1.9976x; 1.9976x over previous
//
#include <hip/hip_runtime.h>
#include <math.h>

#define NN 100000
#define NE 1600000
#define D 64
#define NQ (NE / 4)

#define NBD 196                     // dst buckets, width 512 (dst>>9)
#define CAPD 10240                  // slab capacity (mean 8192, sd 90: +22 sigma)
#define NBS 391                     // src buckets, width 256 (src>>8)
#define CAPS 5120                   // slab capacity (mean 4096, sd 64: +16 sigma)

#define KB 250                      // partition blocks
#define QPB (NQ / KB)               // 1600 int4 quads per block (exact)

typedef _Float16 h4v __attribute__((ext_vector_type(4)));
typedef _Float16 h8v __attribute__((ext_vector_type(8)));

// ---------------- K1: two-pass partition with bulk slab reservation ----------------
// pass a: LDS hist of this block's contiguous slice; reserve per-bucket ranges with
// ONE global atomicAdd per (block,bucket); pass b: re-read slice (cache-hot), scatter.
// Leaves gcurD/gcurS = per-bucket totals.
__global__ __launch_bounds__(256) void partition_kernel(
    const int* __restrict__ src, const int* __restrict__ dst,
    int* __restrict__ gcurD, int* __restrict__ gcurS,
    int* __restrict__ pbuf, unsigned char* __restrict__ qloc)
{
    __shared__ int hD[NBD], hS[NBS];
    int t = threadIdx.x, b = blockIdx.x;
    for (int i = t; i < NBD; i += 256) hD[i] = 0;
    for (int i = t; i < NBS; i += 256) hS[i] = 0;
    __syncthreads();
    const int4* s4 = (const int4*)src + (size_t)b * QPB;
    const int4* d4 = (const int4*)dst + (size_t)b * QPB;
    for (int i = t; i < QPB; i += 256) {
        int4 a = s4[i], d = d4[i];
        atomicAdd(&hD[d.x >> 9], 1); atomicAdd(&hD[d.y >> 9], 1);
        atomicAdd(&hD[d.z >> 9], 1); atomicAdd(&hD[d.w >> 9], 1);
        atomicAdd(&hS[a.x >> 8], 1); atomicAdd(&hS[a.y >> 8], 1);
        atomicAdd(&hS[a.z >> 8], 1); atomicAdd(&hS[a.w >> 8], 1);
    }
    __syncthreads();
    for (int i = t; i < NBD; i += 256) {
        int c = hD[i];
        int base = c ? atomicAdd(&gcurD[i], c) : 0;
        hD[i] = i * CAPD + base;                    // becomes write cursor
    }
    for (int i = t; i < NBS; i += 256) {
        int c = hS[i];
        int base = c ? atomicAdd(&gcurS[i], c) : 0;
        hS[i] = i * CAPS + base;
    }
    __syncthreads();
    for (int i = t; i < QPB; i += 256) {
        int4 a = s4[i], d = d4[i];
        int p;
        p = atomicAdd(&hD[d.x >> 9], 1); pbuf[p] = ((d.x & 511) << 17) | a.x;
        p = atomicAdd(&hD[d.y >> 9], 1); pbuf[p] = ((d.y & 511) << 17) | a.y;
        p = atomicAdd(&hD[d.z >> 9], 1); pbuf[p] = ((d.z & 511) << 17) | a.z;
        p = atomicAdd(&hD[d.w >> 9], 1); pbuf[p] = ((d.w & 511) << 17) | a.w;
        p = atomicAdd(&hS[a.x >> 8], 1); qloc[p] = (unsigned char)(a.x & 255);
        p = atomicAdd(&hS[a.y >> 8], 1); qloc[p] = (unsigned char)(a.y & 255);
        p = atomicAdd(&hS[a.z >> 8], 1); qloc[p] = (unsigned char)(a.z & 255);
        p = atomicAdd(&hS[a.w >> 8], 1); qloc[p] = (unsigned char)(a.w & 255);
    }
}

// ---------------- K2: finalize ----------------
// blocks [0,NBD): dst slab -> row_ptr, ndst, esrc (CSR); [NBD,NBD+NBS): qloc -> nsrc
__global__ __launch_bounds__(256) void finalize_kernel(
    const int* __restrict__ pbuf, const unsigned char* __restrict__ qloc,
    const int* __restrict__ gcurD, const int* __restrict__ gcurS,
    int* __restrict__ row_ptr, float* __restrict__ nsrc,
    float* __restrict__ ndst, int* __restrict__ esrc)
{
    int B = blockIdx.x, t = threadIdx.x;
    int lane = t & 63, w = t >> 6;
    if (B >= NBD) {
        __shared__ int h[256];
        int q = B - NBD;
        int cnt = gcurS[q];
        const unsigned char* slab = qloc + (size_t)q * CAPS;
        h[t] = 0;
        __syncthreads();
        for (int i = t; i < cnt; i += 256) atomicAdd(&h[slab[i]], 1);
        __syncthreads();
        int n = (q << 8) + t;
        if (n < NN) nsrc[n] = 1.0f / sqrtf(fmaxf((float)h[t], 1.0f));
        return;
    }
    __shared__ int fh[512], fcur[512];
    __shared__ int sbeg;
    int cnt = gcurD[B];
    const int* slab = pbuf + (size_t)B * CAPD;
    for (int i = t; i < 512; i += 256) fh[i] = 0;
    if (w == 0) {                                   // bucket base = prefix of totals
        int s = 0;
        for (int j = lane; j < B; j += 64) s += gcurD[j];
        for (int o = 32; o > 0; o >>= 1) s += __shfl_xor(s, o, 64);
        if (lane == 0) sbeg = s;
    }
    if (B == 0 && t == 128) row_ptr[NN] = NE;
    __syncthreads();
    int beg = sbeg;
    for (int i = t; i < cnt; i += 256) atomicAdd(&fh[slab[i] >> 17], 1);
    __syncthreads();
    if (w == 0) {                                   // 512-bin scan, 8 bins/lane
        int v[8];
        int s = 0;
#pragma unroll
        for (int j = 0; j < 8; ++j) { v[j] = fh[lane * 8 + j]; s += v[j]; }
        int incl = s;
        for (int o = 1; o < 64; o <<= 1) {
            int u = __shfl_up(incl, o, 64);
            if (lane >= o) incl += u;
        }
        int run = incl - s;
#pragma unroll
        for (int j = 0; j < 8; ++j) {
            int bin = lane * 8 + j;
            fcur[bin] = run;
            int n = (B << 9) + bin;
            if (n < NN) {
                row_ptr[n] = beg + run;
                ndst[n] = 1.0f / sqrtf(fmaxf((float)v[j], 1.0f));
            }
            run += v[j];
        }
    }
    __syncthreads();
    for (int i = t; i < cnt; i += 256) {
        int v = slab[i];
        int p = atomicAdd(&fcur[v >> 17], 1);
        esrc[beg + p] = v & 0x1FFFF;
    }
}

// ---------------- dense transform: t[v] = fp16( nsrc[v] * (xin[v] @ W) ) ----------------
__global__ __launch_bounds__(256) void transform_kernel(const float* __restrict__ xin,
                                                        const float* __restrict__ W,
                                                        const float* __restrict__ nsrc,
                                                        _Float16* __restrict__ out) {
    __shared__ float Wlds[D * D];
    for (int i = threadIdx.x; i < D * D; i += 256) Wlds[i] = W[i];
    __syncthreads();
    int wave = (blockIdx.x * 256 + threadIdx.x) >> 6;
    int lane = threadIdx.x & 63;
    int g = lane >> 4, c = lane & 15;
    int node0 = wave * 4;
    if (node0 >= NN) return;
    int node = node0 + g;
    float4 xv = *(const float4*)(xin + (size_t)node * D + (c << 2));
    float4 acc = {0.f, 0.f, 0.f, 0.f};
#pragma unroll
    for (int k = 0; k < D; ++k) {
        int srcl = (g << 4) | (k >> 2);
        float comp = ((k & 3) == 0) ? xv.x : ((k & 3) == 1) ? xv.y
                   : ((k & 3) == 2) ? xv.z : xv.w;
        float xk = __shfl(comp, srcl, 64);
        float4 w4 = *(const float4*)(Wlds + k * D + (c << 2));
        acc.x += xk * w4.x; acc.y += xk * w4.y;
        acc.z += xk * w4.z; acc.w += xk * w4.w;
    }
    float sc = nsrc[node];
    h4v o;
    o[0] = (_Float16)(acc.x * sc); o[1] = (_Float16)(acc.y * sc);
    o[2] = (_Float16)(acc.z * sc); o[3] = (_Float16)(acc.w * sc);
    *(h4v*)(out + (size_t)node * D + (c << 2)) = o;
}

// ---------------- aggregation (fp16 gather, fp32 accumulate) ----------------
template<int RELU>
__global__ __launch_bounds__(256) void aggregate_kernel(const _Float16* __restrict__ t,
                                                        const int* __restrict__ row_ptr,
                                                        const int* __restrict__ esrc,
                                                        const float* __restrict__ ndst,
                                                        const float* __restrict__ bias,
                                                        float* __restrict__ out) {
    int node = (blockIdx.x * 256 + threadIdx.x) >> 6;
    int lane = threadIdx.x & 63;
    int g = lane >> 3, c = lane & 7;
    if (node >= NN) return;
    int beg = row_ptr[node], end = row_ptr[node + 1];
    float a0[8] = {0,0,0,0,0,0,0,0};
    float a1[8] = {0,0,0,0,0,0,0,0};
    int i = beg;
    for (; i + 16 <= end; i += 16) {
        int s0 = esrc[i + g];
        int s1 = esrc[i + 8 + g];
        h8v v0 = *(const h8v*)(t + (size_t)s0 * D + (c << 3));
        h8v v1 = *(const h8v*)(t + (size_t)s1 * D + (c << 3));
#pragma unroll
        for (int j = 0; j < 8; ++j) { a0[j] += (float)v0[j]; a1[j] += (float)v1[j]; }
    }
    for (; i < end; i += 8) {
        int e = i + g;
        if (e < end) {
            int s = esrc[e];
            h8v v = *(const h8v*)(t + (size_t)s * D + (c << 3));
#pragma unroll
            for (int j = 0; j < 8; ++j) a0[j] += (float)v[j];
        }
    }
#pragma unroll
    for (int j = 0; j < 8; ++j) a0[j] += a1[j];
#pragma unroll
    for (int j = 0; j < 8; ++j) {
        a0[j] += __shfl_xor(a0[j], 8, 64);
        a0[j] += __shfl_xor(a0[j], 16, 64);
        a0[j] += __shfl_xor(a0[j], 32, 64);
    }
    float nd = ndst[node];
    float4 blo = *(const float4*)(bias + (c << 3));
    float4 bhi = *(const float4*)(bias + (c << 3) + 4);
    float h[8];
    h[0] = a0[0] * nd + blo.x; h[1] = a0[1] * nd + blo.y;
    h[2] = a0[2] * nd + blo.z; h[3] = a0[3] * nd + blo.w;
    h[4] = a0[4] * nd + bhi.x; h[5] = a0[5] * nd + bhi.y;
    h[6] = a0[6] * nd + bhi.z; h[7] = a0[7] * nd + bhi.w;
    if (RELU) {
#pragma unroll
        for (int j = 0; j < 8; ++j) h[j] = fmaxf(h[j], 0.f);
    }
    if (g == 0) {
        float4 o0 = {h[0], h[1], h[2], h[3]};
        float4 o1 = {h[4], h[5], h[6], h[7]};
        *(float4*)(out + (size_t)node * D + (c << 3)) = o0;
        *(float4*)(out + (size_t)node * D + (c << 3) + 4) = o1;
    }
}

// ---------------- launcher ----------------
extern "C" void kernel_launch(void* const* d_in, const int* in_sizes, int n_in,
                              void* d_out, int out_size, void* d_ws, size_t ws_size,
                              hipStream_t stream) {
    const float* x  = (const float*)d_in[0];
    const int* src  = (const int*)d_in[1];
    const int* dst  = (const int*)d_in[2];
    const float* W1 = (const float*)d_in[3];
    const float* b1 = (const float*)d_in[4];
    const float* W2 = (const float*)d_in[5];
    const float* b2 = (const float*)d_in[6];
    float* out = (float*)d_out;

    size_t off = 0;
    auto alloc = [&](size_t bytes) -> void* {
        void* p = (char*)d_ws + off;
        off += (bytes + 255) & ~(size_t)255;
        return p;
    };
    int* row_ptr  = (int*)alloc((size_t)(NN + 1) * 4);
    float* nsrc   = (float*)alloc((size_t)NN * 4);
    float* ndst   = (float*)alloc((size_t)NN * 4);
    int* gcurD    = (int*)alloc((size_t)(NBD + NBS) * 4);
    int* esrc     = (int*)alloc((size_t)NE * 4);                 // 6.4 MB
    _Float16* t_h = (_Float16*)alloc((size_t)NN * D * 2);        // 12.8 MB
    float* h1     = (float*)alloc((size_t)NN * D * 4);           // 25.6 MB
    (void)ws_size;
    int* gcurS = gcurD + NBD;

    // prep scratch aliases h1 (dead until aggregate1 writes it):
    // pbuf 196*10240*4 = 8.0MB | qloc 391*5120 = 2.0MB  -> 10MB < 25.6MB
    int* pbuf = (int*)h1;
    unsigned char* qloc = (unsigned char*)(pbuf + (size_t)NBD * CAPD);

    hipMemsetAsync(gcurD, 0, (size_t)(NBD + NBS) * 4, stream);

    const int TB = 256;
    partition_kernel<<<KB, TB, 0, stream>>>(src, dst, gcurD, gcurS, pbuf, qloc);
    finalize_kernel<<<NBD + NBS, TB, 0, stream>>>(pbuf, qloc, gcurD, gcurS,
                                                  row_ptr, nsrc, ndst, esrc);

    int tf_blocks = NN / 16;
    int ag_blocks = NN / 4;
    transform_kernel<<<tf_blocks, TB, 0, stream>>>(x, W1, nsrc, t_h);
    aggregate_kernel<1><<<ag_blocks, TB, 0, stream>>>(t_h, row_ptr, esrc, ndst, b1, h1);
    transform_kernel<<<tf_blocks, TB, 0, stream>>>(h1, W2, nsrc, t_h);
    aggregate_kernel<0><<<ag_blocks, TB, 0, stream>>>(t_h, row_ptr, esrc, ndst, b2, out);
}

// Round 11
// 275.764 us; speedup vs baseline: 2.1111x; 1.0568x over previous
//
#include <hip/hip_runtime.h>
#include <math.h>

#define NN 100000
#define NE 1600000
#define D 64
#define NQ (NE / 4)

#define NBD 196                     // dst buckets, width 512 (dst>>9)
#define CAPD 10240                  // slab capacity (mean 8192, sd 90: +22 sigma)
#define NBS 391                     // src buckets, width 256 (src>>8)
#define CAPS 5120                   // slab capacity (mean 4096, sd 64: +16 sigma)

#define KB 250                      // partition blocks
#define QPB (NQ / KB)               // 1600 int4 quads per block (exact)
#define TFB (NN / 16)               // 6250 transform blocks (4 nodes/wave, 4 waves)

typedef _Float16 h4v __attribute__((ext_vector_type(4)));
typedef _Float16 h8v __attribute__((ext_vector_type(8)));

// ---------------- K1 (fused): blocks [0,KB) partition | [KB,KB+TFB) transform1 --------
// Partition: two-pass slab sort with bulk reservation (r10, proven).
// Transform1: t_h = fp16(x @ W1)  — NO nsrc (applied per-edge in aggregate-1, r8-proven),
// so it is independent of graph prep and overlaps partition's latency-bound phases.
__global__ __launch_bounds__(256) void partition_tf1_kernel(
    const int* __restrict__ src, const int* __restrict__ dst,
    int* __restrict__ gcurD, int* __restrict__ gcurS,
    int* __restrict__ pbuf, unsigned char* __restrict__ qloc,
    const float* __restrict__ x, const float* __restrict__ W1,
    _Float16* __restrict__ t_h)
{
    int t = threadIdx.x, b = blockIdx.x;
    if (b >= KB) {
        // ---- transform1 ----
        __shared__ float Wlds[D * D];
        for (int i = t; i < D * D; i += 256) Wlds[i] = W1[i];
        __syncthreads();
        int wave = ((b - KB) * 256 + t) >> 6;
        int lane = t & 63;
        int g = lane >> 4, c = lane & 15;
        int node = wave * 4 + g;                    // wave*4 < NN guaranteed (TFB exact)
        float4 xv = *(const float4*)(x + (size_t)node * D + (c << 2));
        float4 acc = {0.f, 0.f, 0.f, 0.f};
#pragma unroll
        for (int k = 0; k < D; ++k) {
            int srcl = (g << 4) | (k >> 2);
            float comp = ((k & 3) == 0) ? xv.x : ((k & 3) == 1) ? xv.y
                       : ((k & 3) == 2) ? xv.z : xv.w;
            float xk = __shfl(comp, srcl, 64);
            float4 w4 = *(const float4*)(Wlds + k * D + (c << 2));
            acc.x += xk * w4.x; acc.y += xk * w4.y;
            acc.z += xk * w4.z; acc.w += xk * w4.w;
        }
        h4v o;
        o[0] = (_Float16)acc.x; o[1] = (_Float16)acc.y;
        o[2] = (_Float16)acc.z; o[3] = (_Float16)acc.w;
        *(h4v*)(t_h + (size_t)node * D + (c << 2)) = o;
        return;
    }
    // ---- partition ----
    __shared__ int hD[NBD], hS[NBS];
    for (int i = t; i < NBD; i += 256) hD[i] = 0;
    for (int i = t; i < NBS; i += 256) hS[i] = 0;
    __syncthreads();
    const int4* s4 = (const int4*)src + (size_t)b * QPB;
    const int4* d4 = (const int4*)dst + (size_t)b * QPB;
    for (int i = t; i < QPB; i += 256) {
        int4 a = s4[i], d = d4[i];
        atomicAdd(&hD[d.x >> 9], 1); atomicAdd(&hD[d.y >> 9], 1);
        atomicAdd(&hD[d.z >> 9], 1); atomicAdd(&hD[d.w >> 9], 1);
        atomicAdd(&hS[a.x >> 8], 1); atomicAdd(&hS[a.y >> 8], 1);
        atomicAdd(&hS[a.z >> 8], 1); atomicAdd(&hS[a.w >> 8], 1);
    }
    __syncthreads();
    for (int i = t; i < NBD; i += 256) {
        int c = hD[i];
        int base = c ? atomicAdd(&gcurD[i], c) : 0;
        hD[i] = i * CAPD + base;                    // becomes write cursor
    }
    for (int i = t; i < NBS; i += 256) {
        int c = hS[i];
        int base = c ? atomicAdd(&gcurS[i], c) : 0;
        hS[i] = i * CAPS + base;
    }
    __syncthreads();
    for (int i = t; i < QPB; i += 256) {
        int4 a = s4[i], d = d4[i];
        int p;
        p = atomicAdd(&hD[d.x >> 9], 1); pbuf[p] = ((d.x & 511) << 17) | a.x;
        p = atomicAdd(&hD[d.y >> 9], 1); pbuf[p] = ((d.y & 511) << 17) | a.y;
        p = atomicAdd(&hD[d.z >> 9], 1); pbuf[p] = ((d.z & 511) << 17) | a.z;
        p = atomicAdd(&hD[d.w >> 9], 1); pbuf[p] = ((d.w & 511) << 17) | a.w;
        p = atomicAdd(&hS[a.x >> 8], 1); qloc[p] = (unsigned char)(a.x & 255);
        p = atomicAdd(&hS[a.y >> 8], 1); qloc[p] = (unsigned char)(a.y & 255);
        p = atomicAdd(&hS[a.z >> 8], 1); qloc[p] = (unsigned char)(a.z & 255);
        p = atomicAdd(&hS[a.w >> 8], 1); qloc[p] = (unsigned char)(a.w & 255);
    }
}

// ---------------- K2: finalize (r10, proven) ----------------
__global__ __launch_bounds__(256) void finalize_kernel(
    const int* __restrict__ pbuf, const unsigned char* __restrict__ qloc,
    const int* __restrict__ gcurD, const int* __restrict__ gcurS,
    int* __restrict__ row_ptr, float* __restrict__ nsrc,
    float* __restrict__ ndst, int* __restrict__ esrc)
{
    int B = blockIdx.x, t = threadIdx.x;
    int lane = t & 63, w = t >> 6;
    if (B >= NBD) {
        __shared__ int h[256];
        int q = B - NBD;
        int cnt = gcurS[q];
        const unsigned char* slab = qloc + (size_t)q * CAPS;
        h[t] = 0;
        __syncthreads();
        for (int i = t; i < cnt; i += 256) atomicAdd(&h[slab[i]], 1);
        __syncthreads();
        int n = (q << 8) + t;
        if (n < NN) nsrc[n] = 1.0f / sqrtf(fmaxf((float)h[t], 1.0f));
        return;
    }
    __shared__ int fh[512], fcur[512];
    __shared__ int sbeg;
    int cnt = gcurD[B];
    const int* slab = pbuf + (size_t)B * CAPD;
    for (int i = t; i < 512; i += 256) fh[i] = 0;
    if (w == 0) {
        int s = 0;
        for (int j = lane; j < B; j += 64) s += gcurD[j];
        for (int o = 32; o > 0; o >>= 1) s += __shfl_xor(s, o, 64);
        if (lane == 0) sbeg = s;
    }
    if (B == 0 && t == 128) row_ptr[NN] = NE;
    __syncthreads();
    int beg = sbeg;
    for (int i = t; i < cnt; i += 256) atomicAdd(&fh[slab[i] >> 17], 1);
    __syncthreads();
    if (w == 0) {
        int v[8];
        int s = 0;
#pragma unroll
        for (int j = 0; j < 8; ++j) { v[j] = fh[lane * 8 + j]; s += v[j]; }
        int incl = s;
        for (int o = 1; o < 64; o <<= 1) {
            int u = __shfl_up(incl, o, 64);
            if (lane >= o) incl += u;
        }
        int run = incl - s;
#pragma unroll
        for (int j = 0; j < 8; ++j) {
            int bin = lane * 8 + j;
            fcur[bin] = run;
            int n = (B << 9) + bin;
            if (n < NN) {
                row_ptr[n] = beg + run;
                ndst[n] = 1.0f / sqrtf(fmaxf((float)v[j], 1.0f));
            }
            run += v[j];
        }
    }
    __syncthreads();
    for (int i = t; i < cnt; i += 256) {
        int v = slab[i];
        int p = atomicAdd(&fcur[v >> 17], 1);
        esrc[beg + p] = v & 0x1FFFF;
    }
}

// ---------------- dense transform (layer 2): t[v] = fp16( nsrc[v] * (xin[v] @ W) ) ------
__global__ __launch_bounds__(256) void transform_kernel(const float* __restrict__ xin,
                                                        const float* __restrict__ W,
                                                        const float* __restrict__ nsrc,
                                                        _Float16* __restrict__ out) {
    __shared__ float Wlds[D * D];
    for (int i = threadIdx.x; i < D * D; i += 256) Wlds[i] = W[i];
    __syncthreads();
    int wave = (blockIdx.x * 256 + threadIdx.x) >> 6;
    int lane = threadIdx.x & 63;
    int g = lane >> 4, c = lane & 15;
    int node0 = wave * 4;
    if (node0 >= NN) return;
    int node = node0 + g;
    float4 xv = *(const float4*)(xin + (size_t)node * D + (c << 2));
    float4 acc = {0.f, 0.f, 0.f, 0.f};
#pragma unroll
    for (int k = 0; k < D; ++k) {
        int srcl = (g << 4) | (k >> 2);
        float comp = ((k & 3) == 0) ? xv.x : ((k & 3) == 1) ? xv.y
                   : ((k & 3) == 2) ? xv.z : xv.w;
        float xk = __shfl(comp, srcl, 64);
        float4 w4 = *(const float4*)(Wlds + k * D + (c << 2));
        acc.x += xk * w4.x; acc.y += xk * w4.y;
        acc.z += xk * w4.z; acc.w += xk * w4.w;
    }
    float sc = nsrc[node];
    h4v o;
    o[0] = (_Float16)(acc.x * sc); o[1] = (_Float16)(acc.y * sc);
    o[2] = (_Float16)(acc.z * sc); o[3] = (_Float16)(acc.w * sc);
    *(h4v*)(out + (size_t)node * D + (c << 2)) = o;
}

// ---------------- aggregation (fp16 gather, fp32 accumulate; r8-proven) ----------------
template<int RELU, int USE_NSRC>
__global__ __launch_bounds__(256) void aggregate_kernel(const _Float16* __restrict__ t,
                                                        const int* __restrict__ row_ptr,
                                                        const int* __restrict__ esrc,
                                                        const float* __restrict__ nsrc,
                                                        const float* __restrict__ ndst,
                                                        const float* __restrict__ bias,
                                                        float* __restrict__ out) {
    int node = (blockIdx.x * 256 + threadIdx.x) >> 6;
    int lane = threadIdx.x & 63;
    int g = lane >> 3, c = lane & 7;
    if (node >= NN) return;
    int beg = row_ptr[node], end = row_ptr[node + 1];
    float a0[8] = {0,0,0,0,0,0,0,0};
    float a1[8] = {0,0,0,0,0,0,0,0};
    int i = beg;
    for (; i + 16 <= end; i += 16) {
        int s0 = esrc[i + g];
        int s1 = esrc[i + 8 + g];
        float ns0 = USE_NSRC ? nsrc[s0] : 1.0f;
        float ns1 = USE_NSRC ? nsrc[s1] : 1.0f;
        h8v v0 = *(const h8v*)(t + (size_t)s0 * D + (c << 3));
        h8v v1 = *(const h8v*)(t + (size_t)s1 * D + (c << 3));
#pragma unroll
        for (int j = 0; j < 8; ++j) {
            if (USE_NSRC) { a0[j] += (float)v0[j] * ns0; a1[j] += (float)v1[j] * ns1; }
            else          { a0[j] += (float)v0[j];       a1[j] += (float)v1[j]; }
        }
    }
    for (; i < end; i += 8) {
        int e = i + g;
        if (e < end) {
            int s = esrc[e];
            float ns = USE_NSRC ? nsrc[s] : 1.0f;
            h8v v = *(const h8v*)(t + (size_t)s * D + (c << 3));
#pragma unroll
            for (int j = 0; j < 8; ++j) {
                if (USE_NSRC) a0[j] += (float)v[j] * ns;
                else          a0[j] += (float)v[j];
            }
        }
    }
#pragma unroll
    for (int j = 0; j < 8; ++j) a0[j] += a1[j];
#pragma unroll
    for (int j = 0; j < 8; ++j) {
        a0[j] += __shfl_xor(a0[j], 8, 64);
        a0[j] += __shfl_xor(a0[j], 16, 64);
        a0[j] += __shfl_xor(a0[j], 32, 64);
    }
    float nd = ndst[node];
    float4 blo = *(const float4*)(bias + (c << 3));
    float4 bhi = *(const float4*)(bias + (c << 3) + 4);
    float h[8];
    h[0] = a0[0] * nd + blo.x; h[1] = a0[1] * nd + blo.y;
    h[2] = a0[2] * nd + blo.z; h[3] = a0[3] * nd + blo.w;
    h[4] = a0[4] * nd + bhi.x; h[5] = a0[5] * nd + bhi.y;
    h[6] = a0[6] * nd + bhi.z; h[7] = a0[7] * nd + bhi.w;
    if (RELU) {
#pragma unroll
        for (int j = 0; j < 8; ++j) h[j] = fmaxf(h[j], 0.f);
    }
    if (g == 0) {
        float4 o0 = {h[0], h[1], h[2], h[3]};
        float4 o1 = {h[4], h[5], h[6], h[7]};
        *(float4*)(out + (size_t)node * D + (c << 3)) = o0;
        *(float4*)(out + (size_t)node * D + (c << 3) + 4) = o1;
    }
}

// ---------------- launcher ----------------
extern "C" void kernel_launch(void* const* d_in, const int* in_sizes, int n_in,
                              void* d_out, int out_size, void* d_ws, size_t ws_size,
                              hipStream_t stream) {
    const float* x  = (const float*)d_in[0];
    const int* src  = (const int*)d_in[1];
    const int* dst  = (const int*)d_in[2];
    const float* W1 = (const float*)d_in[3];
    const float* b1 = (const float*)d_in[4];
    const float* W2 = (const float*)d_in[5];
    const float* b2 = (const float*)d_in[6];
    float* out = (float*)d_out;

    size_t off = 0;
    auto alloc = [&](size_t bytes) -> void* {
        void* p = (char*)d_ws + off;
        off += (bytes + 255) & ~(size_t)255;
        return p;
    };
    int* row_ptr  = (int*)alloc((size_t)(NN + 1) * 4);
    float* nsrc   = (float*)alloc((size_t)NN * 4);
    float* ndst   = (float*)alloc((size_t)NN * 4);
    int* gcurD    = (int*)alloc((size_t)(NBD + NBS) * 4);
    int* esrc     = (int*)alloc((size_t)NE * 4);                 // 6.4 MB
    _Float16* t_h = (_Float16*)alloc((size_t)NN * D * 2);        // 12.8 MB
    float* h1     = (float*)alloc((size_t)NN * D * 4);           // 25.6 MB
    (void)ws_size;
    int* gcurS = gcurD + NBD;

    // prep scratch aliases h1 (dead until aggregate1 writes it):
    // pbuf 196*10240*4 = 8.0MB | qloc 391*5120 = 2.0MB  -> 10MB < 25.6MB
    int* pbuf = (int*)h1;
    unsigned char* qloc = (unsigned char*)(pbuf + (size_t)NBD * CAPD);

    hipMemsetAsync(gcurD, 0, (size_t)(NBD + NBS) * 4, stream);

    const int TB = 256;
    partition_tf1_kernel<<<KB + TFB, TB, 0, stream>>>(src, dst, gcurD, gcurS,
                                                      pbuf, qloc, x, W1, t_h);
    finalize_kernel<<<NBD + NBS, TB, 0, stream>>>(pbuf, qloc, gcurD, gcurS,
                                                  row_ptr, nsrc, ndst, esrc);

    int ag_blocks = NN / 4;
    aggregate_kernel<1, 1><<<ag_blocks, TB, 0, stream>>>(t_h, row_ptr, esrc, nsrc, ndst, b1, h1);
    transform_kernel<<<NN / 16, TB, 0, stream>>>(h1, W2, nsrc, t_h);
    aggregate_kernel<0, 0><<<ag_blocks, TB, 0, stream>>>(t_h, row_ptr, esrc, nsrc, ndst, b2, out);
}